// Round 22
// baseline (32.844 us; speedup 1.0000x reference)
//
#include <hip/hip_runtime.h>
#include <math.h>

#define TWO_PI_F 6.28318530717958647692f

typedef unsigned int u32;
typedef __attribute__((ext_vector_type(4))) float    f4;
typedef __attribute__((ext_vector_type(16))) float   f16v;
typedef __attribute__((ext_vector_type(2))) float    f2;
typedef __attribute__((ext_vector_type(2))) _Float16 h2;
typedef __attribute__((ext_vector_type(4))) _Float16 h4;
typedef __attribute__((ext_vector_type(8))) _Float16 h8;

union B8 { h8 v; h4 q[2]; };
union C2 { u32 w[2]; h4 v; };
union P4 { h2 a[4]; h8 v; };

#if __has_builtin(__builtin_amdgcn_cvt_pkrtz)
__device__ __forceinline__ h2 CVTPK(float a, float b) {
    return __builtin_bit_cast(h2, __builtin_amdgcn_cvt_pkrtz(a, b));
}
#else
__device__ __forceinline__ h2 CVTPK(float a, float b) {
    return (h2){(_Float16)a, (_Float16)b};
}
#endif

// ---------------------------------------------------------------------------
// r19/r21 structure + FULL register prefetch of loop operands:
// all 8 iterations' P2 words (per-lane b32), peb rows (broadcast h4) and
// L-rows (broadcast f32) are loaded in ONE pipelined burst before the loop
// (latencies overlap); the MFMA loop is then pure register compute.
// This is the last untested mechanism for the ~50% in-wave stall.
// Math: p(h,v) via mfma_f32_32x32x16_f16 (K=16 exact), orientation on the
// A side, relu-split epilogue (|src| fma + separable linear term).
// 2080 upper-triangular 32x32 blocks, 256 threads, 4 MFMAs/iter dual-stream.
// ---------------------------------------------------------------------------
__global__ __launch_bounds__(256, 2) void gd_mfma(
    const float* __restrict__ z,  const float* __restrict__ s,
    const float* __restrict__ W1, const float* __restrict__ b1,
    const float* __restrict__ W2, const float* __restrict__ b2v,
    float* __restrict__ out, int N, int NB)
{
    __shared__ __attribute__((aligned(16))) _Float16 Ald[64][24]; // 3KB
    __shared__ __attribute__((aligned(16))) h4 peb[64];           // 512B
    __shared__ __attribute__((aligned(16))) h2 P2[1024];          // 4KB {ct,st}
    __shared__ __attribute__((aligned(16))) float S[2][32][36];   // 9.2KB
    __shared__ __attribute__((aligned(16))) f4 strig2[64];        // 1KB
    __shared__ __attribute__((aligned(16))) float w2f[64];        // 256B
    __shared__ float Lp[12];                                      // 48B
    __shared__ float LA[64], LB[64];                              // 512B

    // --- triangular block decode: u -> (bi, bj), bj >= bi ---
    int u = blockIdx.x;
    int M = 2 * NB + 1;
    float disc = (float)(M * M - 8 * u);
    int bi = (int)(((float)M - sqrtf(disc)) * 0.5f);
    if (bi < 0) bi = 0;
    if (bi > NB - 1) bi = NB - 1;
    while (bi > 0 && bi * (M - bi) / 2 > u) --bi;
    while ((bi + 1) * (M - (bi + 1)) / 2 <= u) ++bi;
    int bj = bi + (u - bi * (M - bi) / 2);

    int t    = threadIdx.x;
    int lane = t & 63;

    if (t < 64) {                        // wave 0: trig + pe + V^T rows + Lp
        int grow = (t < 32) ? (bi * 32 + t) : (bj * 32 + (t - 32));
        float ang = TWO_PI_F * s[grow];
        float c1 = __cosf(ang), s1 = __sinf(ang);
        float c2 = c1 * c1 - s1 * s1, s2 = 2.0f * c1 * s1;
        strig2[t] = (f4){c1, s1, c2, s2};
        peb[t]    = (h4){(_Float16)c1, (_Float16)s1, (_Float16)c2, (_Float16)s2};
        float w2t = W2[t];
        w2f[t] = w2t;

        float zc = b1[t];
#pragma unroll
        for (int zz = 0; zz < 32; ++zz)
            zc = fmaf(z[zz], W1[(10 + zz) * 64 + t], zc);

        h8 row0, row1;
#pragma unroll
        for (int k = 0; k < 8; ++k) row0[k] = (_Float16)W1[k * 64 + t];
        row1 = (h8)0;
        row1[0] = (_Float16)W1[8 * 64 + t];   // wc
        row1[1] = (_Float16)W1[9 * 64 + t];   // ws
        row1[2] = (_Float16)zc;               // bias via "1" feature
        *(h8*)&Ald[t][0] = row0;
        *(h8*)&Ald[t][8] = row1;

        // Lp[k] = 0.25 * sum_h V[k,h]*w2[h] : 64-lane butterfly (wave 0)
        float q25 = 0.25f * w2t;
        float lv[11];
#pragma unroll
        for (int k = 0; k < 8; ++k) lv[k] = (float)row0[k] * q25;
        lv[8]  = (float)row1[0] * q25;
        lv[9]  = (float)row1[1] * q25;
        lv[10] = zc * q25;
#pragma unroll
        for (int off = 32; off; off >>= 1)
#pragma unroll
            for (int k = 0; k < 11; ++k)
                lv[k] += __shfl_xor(lv[k], off);
        if (t == 0) {
#pragma unroll
            for (int k = 0; k < 11; ++k) Lp[k] = lv[k];
        }
    }
    __syncthreads();

    // --- P2 build (all threads) + LA/LB rows (t<64) ---
    {
        int base = t * 4;
        int il = base >> 5, j0 = base & 31;
        f4 ci = strig2[il];
        P4 pk;
#pragma unroll
        for (int c = 0; c < 4; ++c) {
            f4 cj = strig2[32 + j0 + c];
            float ctv = fmaf(ci.x, cj.x, ci.y * cj.y);
            float stv = fabsf(fmaf(ci.y, cj.x, -(ci.x * cj.y)));
            pk.a[c] = CVTPK(ctv, stv);
        }
        *(h8*)&P2[base] = pk.v;
    }
    if (t < 64) {
        f4 tg = strig2[t];
        LA[t] = fmaf(Lp[0], tg.x, fmaf(Lp[1], tg.y,
                 fmaf(Lp[2], tg.z, fmaf(Lp[3], tg.w, Lp[10]))));
        LB[t] = fmaf(Lp[4], tg.x, fmaf(Lp[5], tg.y,
                 fmaf(Lp[6], tg.z, Lp[7] * tg.w)));
    }

    int n  = lane & 31;
    int q  = lane >> 5;
    int wv = t >> 6;
    int o  = wv >> 1;            // orientation: wave-invariant

    // 0.25*w2 f32 registers matched to C row layout
    float w2v[2][16];
#pragma unroll
    for (int H = 0; H < 2; ++H)
#pragma unroll
        for (int e = 0; e < 16; ++e)
            w2v[H][e] = 0.25f * w2f[(e & 3) + 8 * (e >> 2) + 4 * q + 32 * H];
    __syncthreads();

    // A-frags: o=1 waves swap the k0..3 / k4..7 halves (orientation on A side)
    h8 afr[2];
#pragma unroll
    for (int H = 0; H < 2; ++H) {
        int hh = H * 32 + n;
        B8 af;
        if (q == 0) {
            af.q[0] = *(const h4*)&Ald[hh][o ? 4 : 0];
            af.q[1] = *(const h4*)&Ald[hh][o ? 0 : 4];
        } else {
            af.v = *(const h8*)&Ald[hh][8];
        }
        afr[H] = af.v;
    }

    // --- register prefetch of ALL loop operands (one pipelined burst) ---
    int base = (wv & 1) * 16;    // il base

    h4 pe_col = peb[32 + n];                 // lane's column pe (invariant)
    h4 bq1    = q ? (h4)0 : pe_col;          // B-frag half 2: FULLY invariant
    const float* Lrow = o ? LB : LA;         // hoisted wave-uniform selects
    float laneInv = o ? LA[32 + n] : LB[32 + n];
    float Lp8r = Lp[8], Lp9r = Lp[9];

    u32   pwA_r[8], pwB_r[8];
    h4    varA_r[8], varB_r[8];
    float rowA_r[8], rowB_r[8];
#pragma unroll
    for (int i = 0; i < 8; ++i) {
        pwA_r[i]  = *(const u32*)&P2[(base + i) * 32 + n];
        pwB_r[i]  = *(const u32*)&P2[(base + i + 8) * 32 + n];
        varA_r[i] = peb[base + i];
        varB_r[i] = peb[base + i + 8];
        rowA_r[i] = Lrow[base + i];
        rowB_r[i] = Lrow[base + i + 8];
    }

    // --- phase 2: MFMA loop, pure register operands ---
#pragma unroll
    for (int i = 0; i < 8; ++i) {
        int ilA = base + i;
        int ilB = base + i + 8;

        u32 pwA = pwA_r[i];
        u32 pwB = pwB_r[i];

        B8 bA, bB;
        C2 ccA; ccA.w[0] = pwA; ccA.w[1] = 0x00003C00u;   // {ct,st,1,0}
        C2 ccB; ccB.w[0] = pwB; ccB.w[1] = 0x00003C00u;
        bA.q[0] = q ? ccA.v : varA_r[i];
        bA.q[1] = bq1;
        bB.q[0] = q ? ccB.v : varB_r[i];
        bB.q[1] = bq1;

        f16v a0A = __builtin_amdgcn_mfma_f32_32x32x16_f16(afr[0], bA.v, (f16v)(0.0f), 0, 0, 0);
        f16v a1A = __builtin_amdgcn_mfma_f32_32x32x16_f16(afr[1], bA.v, (f16v)(0.0f), 0, 0, 0);
        f16v a0B = __builtin_amdgcn_mfma_f32_32x32x16_f16(afr[0], bB.v, (f16v)(0.0f), 0, 0, 0);
        f16v a1B = __builtin_amdgcn_mfma_f32_32x32x16_f16(afr[1], bB.v, (f16v)(0.0f), 0, 0, 0);

        float cA0 = 0.f, cA1 = 0.f, cA2 = 0.f, cA3 = 0.f;
        float cB0 = 0.f, cB1 = 0.f, cB2 = 0.f, cB3 = 0.f;
#pragma unroll
        for (int e = 0; e < 8; ++e) {      // |src| is a free VOP3 modifier
            cA0 = fmaf(fabsf(a0A[e]),     w2v[0][e],     cA0);
            cA1 = fmaf(fabsf(a0A[e + 8]), w2v[0][e + 8], cA1);
            cA2 = fmaf(fabsf(a1A[e]),     w2v[1][e],     cA2);
            cA3 = fmaf(fabsf(a1A[e + 8]), w2v[1][e + 8], cA3);
            cB0 = fmaf(fabsf(a0B[e]),     w2v[0][e],     cB0);
            cB1 = fmaf(fabsf(a0B[e + 8]), w2v[0][e + 8], cB1);
            cB2 = fmaf(fabsf(a1B[e]),     w2v[1][e],     cB2);
            cB3 = fmaf(fabsf(a1B[e + 8]), w2v[1][e + 8], cB3);
        }
        float psA = (cA0 + cA1) + (cA2 + cA3);
        float psB = (cB0 + cB1) + (cB2 + cB3);
        psA += __shfl_xor(psA, 32);        // abs part: combine the two K-halves
        psB += __shfl_xor(psB, 32);

        // linear part (exact matmul identity, separable)
        h2 ppA = __builtin_bit_cast(h2, pwA);
        h2 ppB = __builtin_bit_cast(h2, pwB);
        float linA = rowA_r[i] + laneInv;
        linA = fmaf((float)ppA[0], Lp8r, linA);
        linA = fmaf((float)ppA[1], Lp9r, linA);
        float linB = rowB_r[i] + laneInv;
        linB = fmaf((float)ppB[0], Lp8r, linB);
        linB = fmaf((float)ppB[1], Lp9r, linB);
        psA += linA;
        psB += linB;

        if (q == 0) {
            S[o][ilA][n] = psA;
            S[o][ilB][n] = psB;
        }
    }
    __syncthreads();

    // --- phase 3: symmetrized output + mirror (coalesced f4 stores) ---
    float b2 = b2v[0];
    {
        int il = t >> 3;
        int j0 = (t & 7) * 4;
        f4 a = *(const f4*)&S[0][il][j0];
        f4 b = *(const f4*)&S[1][il][j0];
        f4 v;
#pragma unroll
        for (int c = 0; c < 4; ++c) {
            float x = a[c] + b[c] + b2;
            if (bi == bj && il == j0 + c) x = -1e9f;
            v[c] = x;
        }
        *(f4*)&out[(size_t)(bi * 32 + il) * N + bj * 32 + j0] = v;

        if (bj > bi) {
            int jl = t >> 3;
            int i0 = (t & 7) * 4;
            f4 m;
#pragma unroll
            for (int c = 0; c < 4; ++c)
                m[c] = S[0][i0 + c][jl] + S[1][i0 + c][jl] + b2;
            *(f4*)&out[(size_t)(bj * 32 + jl) * N + bi * 32 + i0] = m;
        }
    }
}

extern "C" void kernel_launch(void* const* d_in, const int* in_sizes, int n_in,
                              void* d_out, int out_size, void* d_ws, size_t ws_size,
                              hipStream_t stream) {
    const float* z  = (const float*)d_in[0];  // [32]
    const float* s  = (const float*)d_in[1];  // [N]
    const float* W1 = (const float*)d_in[2];  // [42,64]
    const float* b1 = (const float*)d_in[3];  // [64]
    const float* W2 = (const float*)d_in[4];  // [64]
    const float* b2 = (const float*)d_in[5];  // [1]
    int N = in_sizes[1];                      // 2048

    float* out = (float*)d_out;
    int NB = N / 32;
    int nblk = NB * (NB + 1) / 2;             // 2080 for N=2048
    gd_mfma<<<nblk, 256, 0, stream>>>(z, s, W1, b1, W2, b2, out, N, NB);
}

// Round 23
// 27.024 us; speedup vs baseline: 1.2154x; 1.2154x over previous
//
#include <hip/hip_runtime.h>
#include <math.h>

#define TWO_PI_F 6.28318530717958647692f

typedef unsigned int u32;
typedef __attribute__((ext_vector_type(4))) float    f4;
typedef __attribute__((ext_vector_type(16))) float   f16v;
typedef __attribute__((ext_vector_type(2))) float    f2;
typedef __attribute__((ext_vector_type(2))) _Float16 h2;
typedef __attribute__((ext_vector_type(4))) _Float16 h4;
typedef __attribute__((ext_vector_type(8))) _Float16 h8;

union B8 { h8 v; h4 q[2]; };
union C2 { u32 w[2]; h4 v; };
union P4 { h2 a[4]; h8 v; };

#if __has_builtin(__builtin_amdgcn_cvt_pkrtz)
__device__ __forceinline__ h2 CVTPK(float a, float b) {
    return __builtin_bit_cast(h2, __builtin_amdgcn_cvt_pkrtz(a, b));
}
#else
__device__ __forceinline__ h2 CVTPK(float a, float b) {
    return (h2){(_Float16)a, (_Float16)b};
}
#endif

// ---------------------------------------------------------------------------
// FINAL (revert to best measured: r19/r21, 27.02 us).
// Session summary: 54.6 -> 27.0 us (2.02x). Winning moves:
//  1. Algebraic separation: the N x N x 42 x 64 MLP collapses to a K=16
//     matmul p(h,v) = V^T F via mfma_f32_32x32x16_f16 (r14: 35.7->29.0).
//  2. relu-split epilogue: 0.5*w2*relu(p) = 0.25*w2*p (separable, exact)
//     + 0.25*w2*|p| (|src| is a free VOP3 modifier) (r17: 29.0->27.0).
//  3. Orientation on the A side: o=1 waves swap A-frag k-halves at setup,
//     making B-frag half 2 iteration-invariant (r19).
// Structure: 2080 upper-triangular 32x32 tiles, 256 threads, 4 MFMAs/iter;
// symmetrization computed in-block, mirror tile written via S in LDS.
// Measured-null levers (do not revisit): occupancy either direction,
// explicit ILP, SW pipelining, VGPR-cap lift, setup-hoist kernel,
// B-marshal cuts, 64/512-thread blocks, register operand prefetch.
// ---------------------------------------------------------------------------
__global__ __launch_bounds__(256, 3) void gd_mfma(
    const float* __restrict__ z,  const float* __restrict__ s,
    const float* __restrict__ W1, const float* __restrict__ b1,
    const float* __restrict__ W2, const float* __restrict__ b2v,
    float* __restrict__ out, int N, int NB)
{
    __shared__ __attribute__((aligned(16))) _Float16 Ald[64][24]; // 3KB
    __shared__ __attribute__((aligned(16))) h4 peb[64];           // 512B
    __shared__ __attribute__((aligned(16))) h2 P2[1024];          // 4KB {ct,st}
    __shared__ __attribute__((aligned(16))) float S[2][32][36];   // 9.2KB
    __shared__ __attribute__((aligned(16))) f4 strig2[64];        // 1KB
    __shared__ __attribute__((aligned(16))) float w2f[64];        // 256B
    __shared__ float Lp[12];                                      // 48B
    __shared__ float LA[64], LB[64];                              // 512B

    // --- triangular block decode: u -> (bi, bj), bj >= bi ---
    int u = blockIdx.x;
    int M = 2 * NB + 1;
    float disc = (float)(M * M - 8 * u);
    int bi = (int)(((float)M - sqrtf(disc)) * 0.5f);
    if (bi < 0) bi = 0;
    if (bi > NB - 1) bi = NB - 1;
    while (bi > 0 && bi * (M - bi) / 2 > u) --bi;
    while ((bi + 1) * (M - (bi + 1)) / 2 <= u) ++bi;
    int bj = bi + (u - bi * (M - bi) / 2);

    int t    = threadIdx.x;
    int lane = t & 63;

    if (t < 64) {                        // wave 0: trig + pe + V^T rows + Lp
        int grow = (t < 32) ? (bi * 32 + t) : (bj * 32 + (t - 32));
        float ang = TWO_PI_F * s[grow];
        float c1 = __cosf(ang), s1 = __sinf(ang);
        float c2 = c1 * c1 - s1 * s1, s2 = 2.0f * c1 * s1;
        strig2[t] = (f4){c1, s1, c2, s2};
        peb[t]    = (h4){(_Float16)c1, (_Float16)s1, (_Float16)c2, (_Float16)s2};
        float w2t = W2[t];
        w2f[t] = w2t;

        float zc = b1[t];
#pragma unroll
        for (int zz = 0; zz < 32; ++zz)
            zc = fmaf(z[zz], W1[(10 + zz) * 64 + t], zc);

        h8 row0, row1;
#pragma unroll
        for (int k = 0; k < 8; ++k) row0[k] = (_Float16)W1[k * 64 + t];
        row1 = (h8)0;
        row1[0] = (_Float16)W1[8 * 64 + t];   // wc
        row1[1] = (_Float16)W1[9 * 64 + t];   // ws
        row1[2] = (_Float16)zc;               // bias via "1" feature
        *(h8*)&Ald[t][0] = row0;
        *(h8*)&Ald[t][8] = row1;

        // Lp[k] = 0.25 * sum_h V[k,h]*w2[h] : 64-lane butterfly (wave 0)
        float q25 = 0.25f * w2t;
        float lv[11];
#pragma unroll
        for (int k = 0; k < 8; ++k) lv[k] = (float)row0[k] * q25;
        lv[8]  = (float)row1[0] * q25;
        lv[9]  = (float)row1[1] * q25;
        lv[10] = zc * q25;
#pragma unroll
        for (int off = 32; off; off >>= 1)
#pragma unroll
            for (int k = 0; k < 11; ++k)
                lv[k] += __shfl_xor(lv[k], off);
        if (t == 0) {
#pragma unroll
            for (int k = 0; k < 11; ++k) Lp[k] = lv[k];
        }
    }
    __syncthreads();

    // --- P2 build (all threads) + LA/LB rows (t<64) ---
    {
        int base = t * 4;
        int il = base >> 5, j0 = base & 31;
        f4 ci = strig2[il];
        P4 pk;
#pragma unroll
        for (int c = 0; c < 4; ++c) {
            f4 cj = strig2[32 + j0 + c];
            float ctv = fmaf(ci.x, cj.x, ci.y * cj.y);
            float stv = fabsf(fmaf(ci.y, cj.x, -(ci.x * cj.y)));
            pk.a[c] = CVTPK(ctv, stv);
        }
        *(h8*)&P2[base] = pk.v;
    }
    if (t < 64) {
        f4 tg = strig2[t];
        LA[t] = fmaf(Lp[0], tg.x, fmaf(Lp[1], tg.y,
                 fmaf(Lp[2], tg.z, fmaf(Lp[3], tg.w, Lp[10]))));
        LB[t] = fmaf(Lp[4], tg.x, fmaf(Lp[5], tg.y,
                 fmaf(Lp[6], tg.z, Lp[7] * tg.w)));
    }

    int n  = lane & 31;
    int q  = lane >> 5;
    int wv = t >> 6;
    int o  = wv >> 1;            // orientation: wave-invariant

    // 0.25*w2 f32 registers matched to C row layout
    float w2v[2][16];
#pragma unroll
    for (int H = 0; H < 2; ++H)
#pragma unroll
        for (int e = 0; e < 16; ++e)
            w2v[H][e] = 0.25f * w2f[(e & 3) + 8 * (e >> 2) + 4 * q + 32 * H];
    __syncthreads();

    // A-frags: o=1 waves swap the k0..3 / k4..7 halves (orientation on A side)
    h8 afr[2];
#pragma unroll
    for (int H = 0; H < 2; ++H) {
        int hh = H * 32 + n;
        B8 af;
        if (q == 0) {
            af.q[0] = *(const h4*)&Ald[hh][o ? 4 : 0];
            af.q[1] = *(const h4*)&Ald[hh][o ? 0 : 4];
        } else {
            af.v = *(const h8*)&Ald[hh][8];
        }
        afr[H] = af.v;
    }

    // --- phase 2: dual-stream MFMA loop, o-free B-frags ---
    int base = (wv & 1) * 16;    // il base

    h4 pe_col = peb[32 + n];                 // lane's column pe (invariant)
    h4 bq1    = q ? (h4)0 : pe_col;          // B-frag half 2: FULLY invariant
    const float* Lrow = o ? LB : LA;         // hoisted wave-uniform selects
    float laneInv = o ? LA[32 + n] : LB[32 + n];
    float Lp8r = Lp[8], Lp9r = Lp[9];

#pragma unroll
    for (int i = 0; i < 8; ++i) {
        int ilA = base + i;
        int ilB = base + i + 8;

        h4 varA = peb[ilA];                        // broadcast (uniform addr)
        h4 varB = peb[ilB];
        u32 pwA = *(const u32*)&P2[ilA * 32 + n];  // conflict-free b32
        u32 pwB = *(const u32*)&P2[ilB * 32 + n];
        float rowA = Lrow[ilA];                    // uniform broadcast reads
        float rowB = Lrow[ilB];

        B8 bA, bB;
        C2 ccA; ccA.w[0] = pwA; ccA.w[1] = 0x00003C00u;   // {ct,st,1,0}
        C2 ccB; ccB.w[0] = pwB; ccB.w[1] = 0x00003C00u;
        bA.q[0] = q ? ccA.v : varA;
        bA.q[1] = bq1;
        bB.q[0] = q ? ccB.v : varB;
        bB.q[1] = bq1;

        f16v a0A = __builtin_amdgcn_mfma_f32_32x32x16_f16(afr[0], bA.v, (f16v)(0.0f), 0, 0, 0);
        f16v a1A = __builtin_amdgcn_mfma_f32_32x32x16_f16(afr[1], bA.v, (f16v)(0.0f), 0, 0, 0);
        f16v a0B = __builtin_amdgcn_mfma_f32_32x32x16_f16(afr[0], bB.v, (f16v)(0.0f), 0, 0, 0);
        f16v a1B = __builtin_amdgcn_mfma_f32_32x32x16_f16(afr[1], bB.v, (f16v)(0.0f), 0, 0, 0);

        float cA0 = 0.f, cA1 = 0.f, cA2 = 0.f, cA3 = 0.f;
        float cB0 = 0.f, cB1 = 0.f, cB2 = 0.f, cB3 = 0.f;
#pragma unroll
        for (int e = 0; e < 8; ++e) {      // |src| is a free VOP3 modifier
            cA0 = fmaf(fabsf(a0A[e]),     w2v[0][e],     cA0);
            cA1 = fmaf(fabsf(a0A[e + 8]), w2v[0][e + 8], cA1);
            cA2 = fmaf(fabsf(a1A[e]),     w2v[1][e],     cA2);
            cA3 = fmaf(fabsf(a1A[e + 8]), w2v[1][e + 8], cA3);
            cB0 = fmaf(fabsf(a0B[e]),     w2v[0][e],     cB0);
            cB1 = fmaf(fabsf(a0B[e + 8]), w2v[0][e + 8], cB1);
            cB2 = fmaf(fabsf(a1B[e]),     w2v[1][e],     cB2);
            cB3 = fmaf(fabsf(a1B[e + 8]), w2v[1][e + 8], cB3);
        }
        float psA = (cA0 + cA1) + (cA2 + cA3);
        float psB = (cB0 + cB1) + (cB2 + cB3);
        psA += __shfl_xor(psA, 32);        // abs part: combine the two K-halves
        psB += __shfl_xor(psB, 32);

        // linear part (exact matmul identity, separable)
        h2 ppA = __builtin_bit_cast(h2, pwA);
        h2 ppB = __builtin_bit_cast(h2, pwB);
        float linA = rowA + laneInv;
        linA = fmaf((float)ppA[0], Lp8r, linA);
        linA = fmaf((float)ppA[1], Lp9r, linA);
        float linB = rowB + laneInv;
        linB = fmaf((float)ppB[0], Lp8r, linB);
        linB = fmaf((float)ppB[1], Lp9r, linB);
        psA += linA;
        psB += linB;

        if (q == 0) {
            S[o][ilA][n] = psA;
            S[o][ilB][n] = psB;
        }
    }
    __syncthreads();

    // --- phase 3: symmetrized output + mirror (coalesced f4 stores) ---
    float b2 = b2v[0];
    {
        int il = t >> 3;
        int j0 = (t & 7) * 4;
        f4 a = *(const f4*)&S[0][il][j0];
        f4 b = *(const f4*)&S[1][il][j0];
        f4 v;
#pragma unroll
        for (int c = 0; c < 4; ++c) {
            float x = a[c] + b[c] + b2;
            if (bi == bj && il == j0 + c) x = -1e9f;
            v[c] = x;
        }
        *(f4*)&out[(size_t)(bi * 32 + il) * N + bj * 32 + j0] = v;

        if (bj > bi) {
            int jl = t >> 3;
            int i0 = (t & 7) * 4;
            f4 m;
#pragma unroll
            for (int c = 0; c < 4; ++c)
                m[c] = S[0][i0 + c][jl] + S[1][i0 + c][jl] + b2;
            *(f4*)&out[(size_t)(bj * 32 + jl) * N + bi * 32 + i0] = m;
        }
    }
}

extern "C" void kernel_launch(void* const* d_in, const int* in_sizes, int n_in,
                              void* d_out, int out_size, void* d_ws, size_t ws_size,
                              hipStream_t stream) {
    const float* z  = (const float*)d_in[0];  // [32]
    const float* s  = (const float*)d_in[1];  // [N]
    const float* W1 = (const float*)d_in[2];  // [42,64]
    const float* b1 = (const float*)d_in[3];  // [64]
    const float* W2 = (const float*)d_in[4];  // [64]
    const float* b2 = (const float*)d_in[5];  // [1]
    int N = in_sizes[1];                      // 2048

    float* out = (float*)d_out;
    int NB = N / 32;
    int nblk = NB * (NB + 1) / 2;             // 2080 for N=2048
    gd_mfma<<<nblk, 256, 0, stream>>>(z, s, W1, b1, W2, b2, out, N, NB);
}